// Round 12
// baseline (444.840 us; speedup 1.0000x reference)
//
#include <hip/hip_runtime.h>
#include <hip/hip_bf16.h>

#define NN 8192
#define FIN 256
#define FO 128
#define ROWS 32                 // rows per k_attn block
#define NCH 32                  // 256-col chunks (NN/256)
#define L2E 1.4426950408889634f
#define C2  0.28853900817779268f   // 0.2 * log2(e)

typedef __bf16 bf16x8 __attribute__((ext_vector_type(8)));
typedef __bf16 bf16x2 __attribute__((ext_vector_type(2)));
typedef float  f32x4  __attribute__((ext_vector_type(4)));
typedef unsigned long long u64;
typedef u64 u64x2 __attribute__((ext_vector_type(2)));

// ---------------------------------------------------------------------------
// Kernel 1: FUSED prep = bit-pack adj (blocks 0..2047) + projection
// (blocks 2048..2559). Pack uses the ONLY access shape ever measured at
// 5.2 TB/s in this session (one row per wave, contiguous 1 KB wave-loads,
// r3's k_pack verbatim); proj is the proven k_proj. Fusing lets proj's
// compute ride inside pack's memory-bound phase.
// Bitmask layout (r3): per 256-col group g of row r, 4 u64 words at
// ab[r*128 + g*4 + k]; bit l of word k <-> adj[r][g*256 + l*4 + k].
// ---------------------------------------------------------------------------
__global__ __launch_bounds__(256) void k_prep(
    const float* __restrict__ adj, u64* __restrict__ ab,
    const float* __restrict__ x, const float* __restrict__ W,
    const float* __restrict__ a_src, const float* __restrict__ a_dst,
    __bf16* __restrict__ Bp, float* __restrict__ f_src, float* __restrict__ f_dst)
{
  __shared__ float xs[16 * FIN];     // 16 KB x-tile (proj path only)
  __shared__ float fs[16], fd[16];
  const int tid = threadIdx.x;

  if (blockIdx.x < 2048) {
    // ---------------- pack path (r3 k_pack, proven 5.2 TB/s) ----------------
    const int w = tid >> 6, lane = tid & 63;
    const int row = blockIdx.x * 4 + w;               // 2048 blocks -> 8192 rows
    const float4* src = (const float4*)(adj + (size_t)row * NN) + lane;
    u64* dst = ab + (size_t)row * 128;

    for (int g = 0; g < 32; g += 2) {
      float4 va = src[g * 64];            // wave: contiguous 1 KB
      float4 vb = src[g * 64 + 64];       // second load in flight before ballot wait
      u64 a0 = __ballot(va.x > 0.f);
      u64 a1 = __ballot(va.y > 0.f);
      u64 a2 = __ballot(va.z > 0.f);
      u64 a3 = __ballot(va.w > 0.f);
      if (lane < 4) {
        u64 mv = lane == 0 ? a0 : lane == 1 ? a1 : lane == 2 ? a2 : a3;
        dst[g * 4 + lane] = mv;
      }
      u64 b0 = __ballot(vb.x > 0.f);
      u64 b1 = __ballot(vb.y > 0.f);
      u64 b2 = __ballot(vb.z > 0.f);
      u64 b3 = __ballot(vb.w > 0.f);
      if (lane < 4) {
        u64 mv = lane == 0 ? b0 : lane == 1 ? b1 : lane == 2 ? b2 : b3;
        dst[(g + 1) * 4 + lane] = mv;
      }
    }
    return;
  }

  // ---------------- proj path (k_proj, unchanged) ----------------
  const int i0 = (blockIdx.x - 2048) * 16;

  const float4* xg = (const float4*)(x + (size_t)i0 * FIN);
  float4* xs4 = (float4*)xs;
  #pragma unroll
  for (int t = 0; t < 4; t++) xs4[tid + 256 * t] = xg[tid + 256 * t];
  if (tid < 16) { fs[tid] = 0.f; fd[tid] = 0.f; }
  __syncthreads();

  const int cq = tid & 31;    // column quad: cols c0..c0+3
  const int rg = tid >> 5;    // row group: rows r0, r0+1
  const int c0 = cq * 4;
  const int r0 = rg * 2;
  float acc0[4] = {0.f,0.f,0.f,0.f};
  float acc1[4] = {0.f,0.f,0.f,0.f};
  const float* xr0 = xs + r0 * FIN;
  const float* xr1 = xs + (r0 + 1) * FIN;

  for (int k = 0; k < FIN; k += 4) {
    float4 xa = *(const float4*)(xr0 + k);
    float4 xb = *(const float4*)(xr1 + k);
    #pragma unroll
    for (int kk = 0; kk < 4; kk++) {
      float4 wv = *(const float4*)(W + (size_t)(k + kk) * FO + c0);
      float xav = ((const float*)&xa)[kk];
      float xbv = ((const float*)&xb)[kk];
      acc0[0] += xav * wv.x; acc0[1] += xav * wv.y;
      acc0[2] += xav * wv.z; acc0[3] += xav * wv.w;
      acc1[0] += xbv * wv.x; acc1[1] += xbv * wv.y;
      acc1[2] += xbv * wv.z; acc1[3] += xbv * wv.w;
    }
  }

  float4 as = *(const float4*)(a_src + c0);
  float4 ad = *(const float4*)(a_dst + c0);
  float ps0 = acc0[0]*as.x + acc0[1]*as.y + acc0[2]*as.z + acc0[3]*as.w;
  float ps1 = acc1[0]*as.x + acc1[1]*as.y + acc1[2]*as.z + acc1[3]*as.w;
  float pd0 = acc0[0]*ad.x + acc0[1]*ad.y + acc0[2]*ad.z + acc0[3]*ad.w;
  float pd1 = acc1[0]*ad.x + acc1[1]*ad.y + acc1[2]*ad.z + acc1[3]*ad.w;
  atomicAdd(&fs[r0],     ps0);
  atomicAdd(&fs[r0 + 1], ps1);
  atomicAdd(&fd[r0],     pd0);
  atomicAdd(&fd[r0 + 1], pd1);

  const int j0 = i0 + r0;
  const int kg = j0 >> 5;
  const int q  = (j0 >> 3) & 3;
  const int t0 = j0 & 7;
  #pragma unroll
  for (int c = 0; c < 4; c++) {
    const int n = c0 + c;
    bf16x2 v;
    v[0] = (__bf16)acc0[c];
    v[1] = (__bf16)acc1[c];
    size_t idx = ((size_t)(kg * 8 + (n >> 4)) * 64 + q * 16 + (n & 15)) * 8 + t0;
    *(bf16x2*)(Bp + idx) = v;
  }
  __syncthreads();
  if (tid < 16) { f_src[i0 + tid] = fs[tid]; f_dst[i0 + tid] = fd[tid]; }
}

// ---------------------------------------------------------------------------
// Kernel 2: consumer-only P@H from the bitmask. No producers, no HBM deps:
// masks come from the 8 MB L2/L3-resident ab, prefetched ONE chunk ahead
// into registers (issued at top of phase A so A's ~400cy VALU covers L2/L3
// latency; the per-chunk barrier then drains an already-arrived load).
// r10's proven de-duplicated two-phase core: 8 waves = 2 mt x 4 sq;
// phase A computes 16 DISTINCT a-frags -> LDS af (dbuf); barrier;
// phase B: Bp loads 8-deep + MFMA. Direct divided output. 34 barriers,
// uniform path for all waves.
// ---------------------------------------------------------------------------
__global__ __launch_bounds__(512) void k_attn(
    const u64* __restrict__ ab, const __bf16* __restrict__ Bp,
    const float* __restrict__ f_src, const float* __restrict__ f_dst,
    float* __restrict__ out)
{
  __shared__ __align__(16) float G1[NN];                 // 32 KB
  __shared__ __align__(16) float G2[NN];                 // 32 KB
  __shared__ __align__(16) __bf16 af[2][2][8][64][8];    // 32 KB a-frags
  __shared__ float lsum[ROWS];

  const int tid = threadIdx.x;
  const int w = tid >> 6;
  const int lane = tid & 63;
  const int m = lane & 15;
  const int q = lane >> 4;
  const int i0 = blockIdx.x * ROWS;
  const int mt = w >> 2;              // m-tile: rows mt*16 .. mt*16+15
  const int sq = w & 3;               // phase-A: 64-col step; phase-B: nq quarter

  // prefetch chunk-0 masks first (independent of G build)
  const u64* mrow = ab + (size_t)(i0 + mt * 16 + m) * 128;
  u64x2 Mlo = *(const u64x2*)(mrow);
  u64x2 Mhi = *(const u64x2*)(mrow + 2);

  // G tables for all 8192 cols
  #pragma unroll
  for (int t = 0; t < NN / 512; ++t) {
    int j = t * 512 + tid;
    float d = f_dst[j];
    G1[j] = __builtin_amdgcn_exp2f(d * L2E);
    G2[j] = __builtin_amdgcn_exp2f(d * C2);
  }
  if (tid < ROWS) lsum[tid] = 0.f;
  float s = f_src[i0 + mt * 16 + m];
  const float F1 = __builtin_amdgcn_exp2f(s * L2E);
  const float F2 = __builtin_amdgcn_exp2f(s * C2);

  f32x4 acc0 = (f32x4){0.f, 0.f, 0.f, 0.f};
  f32x4 acc1 = (f32x4){0.f, 0.f, 0.f, 0.f};
  float psum = 0.f;

  __syncthreads();                                 // barrier #0 (G + lsum ready)

  for (int c = 0; c < NCH; ++c) {
    const int cur = c & 1;

    // issue next chunk's mask loads NOW (L2/L3 latency hides under phase A)
    const int cn = (c + 1 < NCH) ? c + 1 : c;
    u64x2 Nlo = *(const u64x2*)(mrow + cn * 4);
    u64x2 Nhi = *(const u64x2*)(mrow + cn * 4 + 2);

    // ---- phase A: my 2 a-frags (task = mt, sq, kg=0..1), computed ONCE
    {
      const u64 M0 = Mlo[0], M1 = Mlo[1], M2 = Mhi[0], M3 = Mhi[1];
      #pragma unroll
      for (int kg = 0; kg < 2; ++kg) {
        const int jj = c * 256 + sq * 64 + kg * 32 + q * 8;
        float4 u0 = *(const float4*)(G1 + jj);
        float4 u1 = *(const float4*)(G1 + jj + 4);
        float4 v0 = *(const float4*)(G2 + jj);
        float4 v1 = *(const float4*)(G2 + jj + 4);
        const unsigned b = sq * 16 + kg * 8 + q * 2;   // bit pos (<=62)
        const unsigned e0 = (unsigned)(M0 >> b);
        const unsigned e1 = (unsigned)(M1 >> b);
        const unsigned e2 = (unsigned)(M2 >> b);
        const unsigned e3 = (unsigned)(M3 >> b);
        float p0 = (e0 & 1u) ? fmaxf(F1 * u0.x, F2 * v0.x) : 0.f;
        float p1 = (e1 & 1u) ? fmaxf(F1 * u0.y, F2 * v0.y) : 0.f;
        float p2 = (e2 & 1u) ? fmaxf(F1 * u0.z, F2 * v0.z) : 0.f;
        float p3 = (e3 & 1u) ? fmaxf(F1 * u0.w, F2 * v0.w) : 0.f;
        float p4 = (e0 & 2u) ? fmaxf(F1 * u1.x, F2 * v1.x) : 0.f;
        float p5 = (e1 & 2u) ? fmaxf(F1 * u1.y, F2 * v1.y) : 0.f;
        float p6 = (e2 & 2u) ? fmaxf(F1 * u1.z, F2 * v1.z) : 0.f;
        float p7 = (e3 & 2u) ? fmaxf(F1 * u1.w, F2 * v1.w) : 0.f;
        psum += ((p0 + p1) + (p2 + p3)) + ((p4 + p5) + (p6 + p7));
        bf16x8 a;
        a[0] = (__bf16)p0; a[1] = (__bf16)p1; a[2] = (__bf16)p2;
        a[3] = (__bf16)p3; a[4] = (__bf16)p4; a[5] = (__bf16)p5;
        a[6] = (__bf16)p6; a[7] = (__bf16)p7;
        *(bf16x8*)&af[cur][mt][sq * 2 + kg][lane][0] = a;
      }
    }
    __syncthreads();             // af[cur] ready (also drains N mask loads)

    // ---- phase B: MFMA my (mt, sq) quarter over the chunk's 8 frags.
    // Bp loads issued 4-deep per half so L2 latency amortizes.
    {
      const __bf16* bch = Bp + (size_t)c * 8 * 4096 + (size_t)(sq * 2) * 512 + lane * 8;
      const bf16x8* afp = (const bf16x8*)&af[cur][mt][0][lane][0];  // frag stride 64
      #pragma unroll
      for (int h = 0; h < 2; ++h) {
        bf16x8 b00 = *(const bf16x8*)(bch + (h * 4 + 0) * 4096);
        bf16x8 b10 = *(const bf16x8*)(bch + (h * 4 + 0) * 4096 + 512);
        bf16x8 b01 = *(const bf16x8*)(bch + (h * 4 + 1) * 4096);
        bf16x8 b11 = *(const bf16x8*)(bch + (h * 4 + 1) * 4096 + 512);
        bf16x8 b02 = *(const bf16x8*)(bch + (h * 4 + 2) * 4096);
        bf16x8 b12 = *(const bf16x8*)(bch + (h * 4 + 2) * 4096 + 512);
        bf16x8 b03 = *(const bf16x8*)(bch + (h * 4 + 3) * 4096);
        bf16x8 b13 = *(const bf16x8*)(bch + (h * 4 + 3) * 4096 + 512);
        bf16x8 a0 = afp[(h * 4 + 0) * 64];
        bf16x8 a1 = afp[(h * 4 + 1) * 64];
        bf16x8 a2 = afp[(h * 4 + 2) * 64];
        bf16x8 a3 = afp[(h * 4 + 3) * 64];
        acc0 = __builtin_amdgcn_mfma_f32_16x16x32_bf16(a0, b00, acc0, 0, 0, 0);
        acc1 = __builtin_amdgcn_mfma_f32_16x16x32_bf16(a0, b10, acc1, 0, 0, 0);
        acc0 = __builtin_amdgcn_mfma_f32_16x16x32_bf16(a1, b01, acc0, 0, 0, 0);
        acc1 = __builtin_amdgcn_mfma_f32_16x16x32_bf16(a1, b11, acc1, 0, 0, 0);
        acc0 = __builtin_amdgcn_mfma_f32_16x16x32_bf16(a2, b02, acc0, 0, 0, 0);
        acc1 = __builtin_amdgcn_mfma_f32_16x16x32_bf16(a2, b12, acc1, 0, 0, 0);
        acc0 = __builtin_amdgcn_mfma_f32_16x16x32_bf16(a3, b03, acc0, 0, 0, 0);
        acc1 = __builtin_amdgcn_mfma_f32_16x16x32_bf16(a3, b13, acc1, 0, 0, 0);
      }
    }

    Mlo = Nlo;                  // loop-carried, static names (rule #20)
    Mhi = Nhi;
  }

  // ---- epilogue: denominators (4 sq-waves per row), direct divided output
  {
    float p = psum;
    p += __shfl_xor(p, 16);
    p += __shfl_xor(p, 32);
    if (lane < 16) atomicAdd(&lsum[mt * 16 + lane], p);
  }
  __syncthreads();              // epilogue barrier (#33)

  const int rr0 = mt * 16 + q * 4;
  #pragma unroll
  for (int r = 0; r < 4; ++r) {
    const float inv = 1.0f / lsum[rr0 + r];
    float* orow = out + (size_t)(i0 + rr0 + r) * FO + (sq * 2) * 16 + m;
    orow[0]  = acc0[r] * inv;
    orow[16] = acc1[r] * inv;
  }
}

extern "C" void kernel_launch(void* const* d_in, const int* in_sizes, int n_in,
                              void* d_out, int out_size, void* d_ws, size_t ws_size,
                              hipStream_t stream) {
  const float* x     = (const float*)d_in[0];
  const float* adj   = (const float*)d_in[1];
  const float* W     = (const float*)d_in[2];
  const float* a_src = (const float*)d_in[3];
  const float* a_dst = (const float*)d_in[4];
  float* out = (float*)d_out;

  char* ws = (char*)d_ws;
  __bf16* Bp   = (__bf16*)ws;                      // 0 .. 2 MB
  float* f_src = (float*)(ws + 2097152);           // 32 KB
  float* f_dst = (float*)(ws + 2097152 + 32768);   // 32 KB
  u64*   ab    = (u64*)(ws + 4194304);             // 4 MB .. 12 MB bitmask

  hipLaunchKernelGGL(k_prep, dim3(2560), dim3(256), 0, stream,
                     adj, ab, x, W, a_src, a_dst, Bp, f_src, f_dst);
  hipLaunchKernelGGL(k_attn, dim3(256), dim3(512), 0, stream,
                     ab, Bp, f_src, f_dst, out);
}

// Round 13
// 395.066 us; speedup vs baseline: 1.1260x; 1.1260x over previous
//
#include <hip/hip_runtime.h>
#include <hip/hip_bf16.h>

#define NN 8192
#define FIN 256
#define FO 128
#define ROWS 32                 // rows per k_attn block
#define NCH 32                  // 256-col chunks (NN/256)
#define L2E 1.4426950408889634f
#define C2  0.28853900817779268f   // 0.2 * log2(e)

typedef __bf16 bf16x8 __attribute__((ext_vector_type(8)));
typedef __bf16 bf16x2 __attribute__((ext_vector_type(2)));
typedef float  f32x4  __attribute__((ext_vector_type(4)));
typedef unsigned long long u64;
typedef u64 u64x2 __attribute__((ext_vector_type(2)));

__device__ __forceinline__ f32x4 ntload(const float* p) {
  return __builtin_nontemporal_load((const f32x4*)p);
}

// ---------------------------------------------------------------------------
// Kernel 1: h = x@W (fp32 accum), write Bpack (bf16 MFMA-B-fragment layout),
//           f_src = h@a_src, f_dst = h@a_dst (fp32).  (unchanged, proven)
// ---------------------------------------------------------------------------
__global__ __launch_bounds__(256) void k_proj(
    const float* __restrict__ x, const float* __restrict__ W,
    const float* __restrict__ a_src, const float* __restrict__ a_dst,
    __bf16* __restrict__ Bp, float* __restrict__ f_src, float* __restrict__ f_dst)
{
  __shared__ float xs[16 * FIN];     // 16 KB x-tile
  __shared__ float fs[16], fd[16];
  const int tid = threadIdx.x;
  const int i0 = blockIdx.x * 16;

  const float4* xg = (const float4*)(x + (size_t)i0 * FIN);
  float4* xs4 = (float4*)xs;
  #pragma unroll
  for (int t = 0; t < 4; t++) xs4[tid + 256 * t] = xg[tid + 256 * t];
  if (tid < 16) { fs[tid] = 0.f; fd[tid] = 0.f; }
  __syncthreads();

  const int cq = tid & 31;    // column quad: cols c0..c0+3
  const int rg = tid >> 5;    // row group: rows r0, r0+1
  const int c0 = cq * 4;
  const int r0 = rg * 2;
  float acc0[4] = {0.f,0.f,0.f,0.f};
  float acc1[4] = {0.f,0.f,0.f,0.f};
  const float* xr0 = xs + r0 * FIN;
  const float* xr1 = xs + (r0 + 1) * FIN;

  for (int k = 0; k < FIN; k += 4) {
    float4 xa = *(const float4*)(xr0 + k);
    float4 xb = *(const float4*)(xr1 + k);
    #pragma unroll
    for (int kk = 0; kk < 4; kk++) {
      float4 wv = *(const float4*)(W + (size_t)(k + kk) * FO + c0);
      float xav = ((const float*)&xa)[kk];
      float xbv = ((const float*)&xb)[kk];
      acc0[0] += xav * wv.x; acc0[1] += xav * wv.y;
      acc0[2] += xav * wv.z; acc0[3] += xav * wv.w;
      acc1[0] += xbv * wv.x; acc1[1] += xbv * wv.y;
      acc1[2] += xbv * wv.z; acc1[3] += xbv * wv.w;
    }
  }

  float4 as = *(const float4*)(a_src + c0);
  float4 ad = *(const float4*)(a_dst + c0);
  float ps0 = acc0[0]*as.x + acc0[1]*as.y + acc0[2]*as.z + acc0[3]*as.w;
  float ps1 = acc1[0]*as.x + acc1[1]*as.y + acc1[2]*as.z + acc1[3]*as.w;
  float pd0 = acc0[0]*ad.x + acc0[1]*ad.y + acc0[2]*ad.z + acc0[3]*ad.w;
  float pd1 = acc1[0]*ad.x + acc1[1]*ad.y + acc1[2]*ad.z + acc1[3]*ad.w;
  atomicAdd(&fs[r0],     ps0);
  atomicAdd(&fs[r0 + 1], ps1);
  atomicAdd(&fd[r0],     pd0);
  atomicAdd(&fd[r0 + 1], pd1);

  const int j0 = i0 + r0;
  const int kg = j0 >> 5;
  const int q  = (j0 >> 3) & 3;
  const int t0 = j0 & 7;
  #pragma unroll
  for (int c = 0; c < 4; c++) {
    const int n = c0 + c;
    bf16x2 v;
    v[0] = (__bf16)acc0[c];
    v[1] = (__bf16)acc1[c];
    size_t idx = ((size_t)(kg * 8 + (n >> 4)) * 64 + q * 16 + (n & 15)) * 8 + t0;
    *(bf16x2*)(Bp + idx) = v;
  }
  __syncthreads();
  if (tid < 16) { f_src[i0 + tid] = fs[tid]; f_dst[i0 + tid] = fd[tid]; }
}

// ---------------------------------------------------------------------------
// Kernel 2: single software-pipelined pack+consume P@H, 16 waves (4/SIMD).
// Round-12 accounting: core ~105us = VALU ~25 + UNMODELED Bp-L2 BW
// (128KB/chunk/CU, 2x redundant, ~2300cy/chunk ~30us) + latency exposed at
// 2 waves/SIMD + barriers. Fixes, one structure:
//  - 1024 thr / 16 waves, ~84KB LDS -> 1 blk/CU but 4 waves/SIMD (2x hiding)
//  - per chunk, uniform roles: PACK (each wave ballots its own 2 adj rows,
//    loaded 2 chunks ahead into static regs; sequential-march shape; masks
//    in 1.5KB single-slot LDS, WAR-safe via existing barriers) | bar |
//    PHASE A (16 waves x 1 distinct a-frag -> af LDS; per-wave VALU halved)
//    | bar | PHASE B (waves = h x nq8: Bp read with ZERO redundancy,
//    64KB/chunk/CU; 4-deep loads; h-partial accs reduced via LDS at end)
//  - refill loads issued LAST in iter -> youngest vmem; ballot's wait (2
//    iters old) and MFMA's Bp waits never force-drain each other.
// HBM floor 3050cy/chunk now exceeds VALU(~1120)/L2(~1150)/LDS(~1000):
// kernel should be adj-BW-bound (~41-55us) + ramp.
// ---------------------------------------------------------------------------
__global__ __launch_bounds__(1024, 4) void k_attn(
    const float* __restrict__ adj, const __bf16* __restrict__ Bp,
    const float* __restrict__ f_src, const float* __restrict__ f_dst,
    float* __restrict__ out)
{
  __shared__ __align__(16) float G1[NN];                 // 32 KB
  __shared__ __align__(16) float G2[NN];                 // 32 KB
  __shared__ __align__(16) u64 msk[ROWS][6];             // 1.5 KB (pad->2-way max)
  __shared__ __align__(16) __bf16 af[2][8][64][8];       // 16 KB a-frags
  __shared__ __align__(16) float ared[2][8][64][4];      // 16 KB h-reduce
  __shared__ float lsum[ROWS];

  const int tid = threadIdx.x;
  const int w = tid >> 6;             // 0..15
  const int lane = tid & 63;
  const int m = lane & 15;
  const int q = lane >> 4;
  const int i0 = blockIdx.x * ROWS;

  // phase-A role: frag (mtA, sqA, kgA); phase-B role: (h, nq8)
  const int mtA = w >> 3;             // 0..1
  const int fA  = w & 7;              // 0..7
  const int sqA = fA >> 1, kgA = fA & 1;
  const int r0l = mtA * 16 + m;
  const int h   = w >> 3;             // kg-half owner in phase B
  const int nq8 = w & 7;              // 16-col output slice

  // ---- prologue: issue chunk-0/1 loads FIRST (hide under G build).
  // Wave w owns rows 2w, 2w+1; each marches sequentially chunk-to-chunk.
  const float* abase = adj + (size_t)(i0 + 2 * w) * NN + lane * 4;
  f32x4 sA0 = ntload(abase);
  f32x4 sA1 = ntload(abase + NN);
  f32x4 sB0 = ntload(abase + 256);
  f32x4 sB1 = ntload(abase + NN + 256);

  // G tables for all 8192 cols
  #pragma unroll
  for (int t = 0; t < NN / 1024; ++t) {
    int j = t * 1024 + tid;
    float d = f_dst[j];
    G1[j] = __builtin_amdgcn_exp2f(d * L2E);
    G2[j] = __builtin_amdgcn_exp2f(d * C2);
  }
  if (tid < ROWS) lsum[tid] = 0.f;
  float s = f_src[i0 + mtA * 16 + m];
  const float F1 = __builtin_amdgcn_exp2f(s * L2E);
  const float F2 = __builtin_amdgcn_exp2f(s * C2);

  f32x4 accP0 = (f32x4){0.f, 0.f, 0.f, 0.f};   // mt=0 partial (my h, nq8)
  f32x4 accP1 = (f32x4){0.f, 0.f, 0.f, 0.f};   // mt=1 partial
  float psum = 0.f;

#define ITER(c, s0, s1)                                                       \
  {                                                                           \
    /* pack chunk c: ballot regs loaded 2 iters ago (wait fully hidden) */    \
    u64 b0 = __ballot(s0[0] > 0.f), b1 = __ballot(s0[1] > 0.f);               \
    u64 b2 = __ballot(s0[2] > 0.f), b3 = __ballot(s0[3] > 0.f);               \
    if (lane < 4) msk[2*w][lane]   = lane==0?b0:lane==1?b1:lane==2?b2:b3;     \
    b0 = __ballot(s1[0] > 0.f); b1 = __ballot(s1[1] > 0.f);                   \
    b2 = __ballot(s1[2] > 0.f); b3 = __ballot(s1[3] > 0.f);                   \
    if (lane < 4) msk[2*w+1][lane] = lane==0?b0:lane==1?b1:lane==2?b2:b3;     \
    __syncthreads();   /* bar1: msk(c) + (iter0: G tables) visible */         \
    /* phase A: my ONE frag (mtA, sqA, kgA) */                                \
    {                                                                         \
      u64x2 Ma = *(const u64x2*)&msk[r0l][0];                                 \
      u64x2 Mb = *(const u64x2*)&msk[r0l][2];                                 \
      const u64 M0 = Ma[0], M1 = Ma[1], M2 = Mb[0], M3 = Mb[1];               \
      const int jj = (c) * 256 + sqA * 64 + kgA * 32 + q * 8;                 \
      float4 u0 = *(const float4*)(G1 + jj);                                  \
      float4 u1 = *(const float4*)(G1 + jj + 4);                              \
      float4 v0 = *(const float4*)(G2 + jj);                                  \
      float4 v1 = *(const float4*)(G2 + jj + 4);                              \
      const unsigned b = sqA * 16 + kgA * 8 + q * 2;                          \
      const unsigned e0 = (unsigned)(M0 >> b);                                \
      const unsigned e1 = (unsigned)(M1 >> b);                                \
      const unsigned e2 = (unsigned)(M2 >> b);                                \
      const unsigned e3 = (unsigned)(M3 >> b);                                \
      float p0 = (e0 & 1u) ? fmaxf(F1 * u0.x, F2 * v0.x) : 0.f;               \
      float p1 = (e1 & 1u) ? fmaxf(F1 * u0.y, F2 * v0.y) : 0.f;               \
      float p2 = (e2 & 1u) ? fmaxf(F1 * u0.z, F2 * v0.z) : 0.f;               \
      float p3 = (e3 & 1u) ? fmaxf(F1 * u0.w, F2 * v0.w) : 0.f;               \
      float p4 = (e0 & 2u) ? fmaxf(F1 * u1.x, F2 * v1.x) : 0.f;               \
      float p5 = (e1 & 2u) ? fmaxf(F1 * u1.y, F2 * v1.y) : 0.f;               \
      float p6 = (e2 & 2u) ? fmaxf(F1 * u1.z, F2 * v1.z) : 0.f;               \
      float p7 = (e3 & 2u) ? fmaxf(F1 * u1.w, F2 * v1.w) : 0.f;               \
      psum += ((p0 + p1) + (p2 + p3)) + ((p4 + p5) + (p6 + p7));              \
      bf16x8 a;                                                               \
      a[0] = (__bf16)p0; a[1] = (__bf16)p1; a[2] = (__bf16)p2;                \
      a[3] = (__bf16)p3; a[4] = (__bf16)p4; a[5] = (__bf16)p5;                \
      a[6] = (__bf16)p6; a[7] = (__bf16)p7;                                   \
      *(bf16x8*)&af[mtA][fA][lane][0] = a;                                    \
    }                                                                         \
    __syncthreads();   /* bar2: af(c) ready */                                \
    /* phase B: zero-redundancy Bp (my h-half of kgIds, my nq8 slice) */      \
    {                                                                         \
      const __bf16* bch = Bp + (size_t)((c) * 8 + h * 4) * 4096               \
                          + (size_t)nq8 * 512 + lane * 8;                     \
      bf16x8 bf0 = *(const bf16x8*)(bch);                                     \
      bf16x8 bf1 = *(const bf16x8*)(bch + 4096);                              \
      bf16x8 bf2 = *(const bf16x8*)(bch + 2 * 4096);                          \
      bf16x8 bf3 = *(const bf16x8*)(bch + 3 * 4096);                          \
      bf16x8 a00 = *(const bf16x8*)&af[0][h*4+0][lane][0];                    \
      bf16x8 a10 = *(const bf16x8*)&af[1][h*4+0][lane][0];                    \
      bf16x8 a01 = *(const bf16x8*)&af[0][h*4+1][lane][0];                    \
      bf16x8 a11 = *(const bf16x8*)&af[1][h*4+1][lane][0];                    \
      bf16x8 a02 = *(const bf16x8*)&af[0][h*4+2][lane][0];                    \
      bf16x8 a12 = *(const bf16x8*)&af[1][h*4+2][lane][0];                    \
      bf16x8 a03 = *(const bf16x8*)&af[0][h*4+3][lane][0];                    \
      bf16x8 a13 = *(const bf16x8*)&af[1][h*4+3][lane][0];                    \
      accP0 = __builtin_amdgcn_mfma_f32_16x16x32_bf16(a00, bf0, accP0, 0,0,0);\
      accP1 = __builtin_amdgcn_mfma_f32_16x16x32_bf16(a10, bf0, accP1, 0,0,0);\
      accP0 = __builtin_amdgcn_mfma_f32_16x16x32_bf16(a01, bf1, accP0, 0,0,0);\
      accP1 = __builtin_amdgcn_mfma_f32_16x16x32_bf16(a11, bf1, accP1, 0,0,0);\
      accP0 = __builtin_amdgcn_mfma_f32_16x16x32_bf16(a02, bf2, accP0, 0,0,0);\
      accP1 = __builtin_amdgcn_mfma_f32_16x16x32_bf16(a12, bf2, accP1, 0,0,0);\
      accP0 = __builtin_amdgcn_mfma_f32_16x16x32_bf16(a03, bf3, accP0, 0,0,0);\
      accP1 = __builtin_amdgcn_mfma_f32_16x16x32_bf16(a13, bf3, accP1, 0,0,0);\
    }                                                                         \
    /* refill: issue chunk c+2 loads LAST (youngest vmem; no FIFO trap) */    \
    if ((c) + 2 < NCH) {                                                      \
      s0 = ntload(abase + ((c) + 2) * 256);                                   \
      s1 = ntload(abase + NN + ((c) + 2) * 256);                              \
    }                                                                         \
  }

  for (int c = 0; c < NCH; c += 2) {
    ITER(c, sA0, sA1)
    ITER(c + 1, sB0, sB1)
  }
#undef ITER

  // ---- epilogue: denominators (8 waves per mt), h-reduce accs, output
  {
    float p = psum;
    p += __shfl_xor(p, 16);
    p += __shfl_xor(p, 32);
    if (lane < 16) atomicAdd(&lsum[mtA * 16 + lane], p);
  }
  if (h == 0) {
    *(f32x4*)&ared[0][nq8][lane][0] = accP0;
    *(f32x4*)&ared[1][nq8][lane][0] = accP1;
  }
  __syncthreads();
  if (h == 1) {
    f32x4 r0v = *(const f32x4*)&ared[0][nq8][lane][0];
    f32x4 r1v = *(const f32x4*)&ared[1][nq8][lane][0];
    f32x4 o0 = accP0 + r0v;      // mt=0 full sum
    f32x4 o1 = accP1 + r1v;      // mt=1 full sum
    #pragma unroll
    for (int r = 0; r < 4; ++r) {
      const int rr = q * 4 + r;
      float inv0 = 1.0f / lsum[rr];
      float inv1 = 1.0f / lsum[16 + rr];
      out[(size_t)(i0 + rr) * FO + nq8 * 16 + m]      = o0[r] * inv0;
      out[(size_t)(i0 + 16 + rr) * FO + nq8 * 16 + m] = o1[r] * inv1;
    }
  }
}

extern "C" void kernel_launch(void* const* d_in, const int* in_sizes, int n_in,
                              void* d_out, int out_size, void* d_ws, size_t ws_size,
                              hipStream_t stream) {
  const float* x     = (const float*)d_in[0];
  const float* adj   = (const float*)d_in[1];
  const float* W     = (const float*)d_in[2];
  const float* a_src = (const float*)d_in[3];
  const float* a_dst = (const float*)d_in[4];
  float* out = (float*)d_out;

  char* ws = (char*)d_ws;
  __bf16* Bp   = (__bf16*)ws;                      // 0 .. 2 MB
  float* f_src = (float*)(ws + 2097152);           // 32 KB
  float* f_dst = (float*)(ws + 2097152 + 32768);   // 32 KB

  hipLaunchKernelGGL(k_proj, dim3(512), dim3(256), 0, stream,
                     x, W, a_src, a_dst, Bp, f_src, f_dst);
  hipLaunchKernelGGL(k_attn, dim3(256), dim3(1024), 0, stream,
                     adj, Bp, f_src, f_dst, out);
}